// Round 5
// baseline (405.127 us; speedup 1.0000x reference)
//
#include <hip/hip_runtime.h>
#include <math.h>

#define B 32
#define L 2048
#define V 512
#define D 512
#define S_CTX 32     // blocks per batch in the fused softmax+context kernel
#define CAP 512      // nnz per batch is exactly 512 -> unique positions <= 512

// ws layout (bytes):
//   0       : int flag (1 = sparse_indices is int64)
//   64      : int cnt[B]
//   1024    : uint claim[B*L]     (256 KB)  dedup map
//   263168  : int  slist[B*CAP]   (64 KB)   compact l-indices
//   328704  : float sval[B*CAP]   (64 KB)   compact raw scores

// alpha = 0 (dense), c = 0, claim = 0, cnt = 0; detect index dtype.
// int64 encoding: odd int32 words in [nnz, 2*nnz) are high halves of idx0 == 0.
// int32 encoding: those words are idx1 values, random in [0, L).
__global__ __launch_bounds__(256) void k_init(float* __restrict__ alpha,
        float* __restrict__ c, unsigned int* __restrict__ claim,
        int* __restrict__ cnt, const int* __restrict__ idx32, int nnz,
        int* __restrict__ flag) {
    int i = blockIdx.x * 256 + threadIdx.x;   // grid covers exactly B*L
    alpha[i] = 0.f;
    claim[i] = 0u;
    if (i < B * D) c[i] = 0.f;
    if (i < B) cnt[i] = 0;
    if (blockIdx.x == 0 && threadIdx.x < 64) {
        int step = nnz / 128; if (step < 1) step = 1;
        int w = nnz + 1 + 2 * threadIdx.x * step;
        unsigned long long nz = __ballot(idx32[w] != 0);
        if (threadIdx.x == 0) *flag = (nz == 0ull) ? 1 : 0;
    }
}

// One wave per nnz entry: claim (b,l) via CAS; winner computes
// dot(bdi[b,l,:], W2) and appends (l, s) to batch b's compact list.
// The reference adds coef*(DHS@W1.T@W2)[b] — constant over the masked set;
// softmax is shift-invariant and scores are not an output, so the entire
// W1/DHS path drops out exactly. Duplicate entries lose the CAS and exit
// before touching the 2 KB row.
__global__ __launch_bounds__(256) void k_scores(const float* __restrict__ bdi,
        const float* __restrict__ W2, const void* __restrict__ idx, int nnz,
        const int* __restrict__ flag, unsigned int* __restrict__ claim,
        int* __restrict__ cnt, int* __restrict__ slist, float* __restrict__ sval) {
    int wave = threadIdx.x >> 6, lane = threadIdx.x & 63;
    int e = blockIdx.x * 4 + wave;
    if (e >= nnz) return;
    int b, l;
    if (*flag) {
        const long long* q = (const long long*)idx;
        b = (int)q[e];
        l = (int)q[nnz + e];
    } else {
        const int* q = (const int*)idx;
        b = q[e];
        l = q[nnz + e];
    }
    int bl = b * L + l;
    int win = 0;
    if (lane == 0) win = (atomicCAS(&claim[bl], 0u, 1u) == 0u) ? 1 : 0;
    win = __shfl(win, 0, 64);
    if (!win) return;
    const float4* row = (const float4*)(bdi + (size_t)bl * V);
    const float4* w   = (const float4*)W2;
    float4 r0 = row[lane],      w0 = w[lane];
    float4 r1 = row[lane + 64], w1 = w[lane + 64];
    float acc = r0.x * w0.x + r0.y * w0.y + r0.z * w0.z + r0.w * w0.w
              + r1.x * w1.x + r1.y * w1.y + r1.z * w1.z + r1.w * w1.w;
    for (int off = 32; off; off >>= 1) acc += __shfl_down(acc, off, 64);
    if (lane == 0) {
        int p = atomicAdd(&cnt[b], 1);
        slist[b * CAP + p] = l;
        sval[b * CAP + p]  = acc;
    }
}

// Fused softmax + alpha scatter + context. Block (b,s): all 32 blocks of a
// batch redundantly reduce the <=512-entry compact list (L2-hot, cheap),
// block s writes alpha for entries j with (j % S_CTX)==s, then accumulates
// its stride of att rows into c via atomics.
__global__ __launch_bounds__(256) void k_ctx(const float* __restrict__ att,
        const int* __restrict__ cnt, const int* __restrict__ slist,
        const float* __restrict__ sval, float* __restrict__ alpha,
        float* __restrict__ c) {
    int b = blockIdx.x / S_CTX, s = blockIdx.x % S_CTX;
    int tid = threadIdx.x;
    __shared__ int   l_s[CAP];
    __shared__ float e_s[CAP];
    __shared__ float red[256];
    int n = cnt[b];
    int j0 = tid, j1 = tid + 256;
    float s0 = -INFINITY, s1 = -INFINITY;
    if (j0 < n) { l_s[j0] = slist[b * CAP + j0]; s0 = sval[b * CAP + j0]; }
    if (j1 < n) { l_s[j1] = slist[b * CAP + j1]; s1 = sval[b * CAP + j1]; }
    red[tid] = fmaxf(s0, s1);
    __syncthreads();
    for (int off = 128; off; off >>= 1) {
        if (tid < off) red[tid] = fmaxf(red[tid], red[tid + off]);
        __syncthreads();
    }
    float m = red[0];
    __syncthreads();
    float e0 = (j0 < n) ? __expf(s0 - m) : 0.f;
    float e1 = (j1 < n) ? __expf(s1 - m) : 0.f;
    if (j0 < n) e_s[j0] = e0;
    if (j1 < n) e_s[j1] = e1;
    red[tid] = e0 + e1;
    __syncthreads();
    for (int off = 128; off; off >>= 1) {
        if (tid < off) red[tid] += red[tid + off];
        __syncthreads();
    }
    float inv = 1.f / red[0];
    // alpha scatter: each entry j written by exactly one of the 32 blocks
    if (j0 < n && (j0 & (S_CTX - 1)) == s) alpha[b * L + l_s[j0]] = e0 * inv;
    if (j1 < n && (j1 & (S_CTX - 1)) == s) alpha[b * L + l_s[j1]] = e1 * inv;
    // context: pairs of rows per iteration, float4 lanes over D=512
    int half = tid >> 7, dq = tid & 127;
    float4 acc = {0.f, 0.f, 0.f, 0.f};
    for (int jj = s * 2; jj < n; jj += S_CTX * 2) {
        int j = jj + half;
        if (j < n) {
            float a = e_s[j] * inv;
            float4 v = *(const float4*)(att + ((size_t)b * L + l_s[j]) * D + dq * 4);
            acc.x += a * v.x;
            acc.y += a * v.y;
            acc.z += a * v.z;
            acc.w += a * v.w;
        }
    }
    float* cb = c + b * D + dq * 4;
    atomicAdd(cb + 0, acc.x);
    atomicAdd(cb + 1, acc.y);
    atomicAdd(cb + 2, acc.z);
    atomicAdd(cb + 3, acc.w);
}

extern "C" void kernel_launch(void* const* d_in, const int* in_sizes, int n_in,
                              void* d_out, int out_size, void* d_ws, size_t ws_size,
                              hipStream_t stream) {
    const float* bdi  = (const float*)d_in[1];
    const float* att  = (const float*)d_in[2];
    const void*  sidx = d_in[3];
    const float* W2   = (const float*)d_in[6];

    float* out   = (float*)d_out;
    float* c     = out;            // [B, D]
    float* alpha = out + B * D;    // [B, L] (== [B,L,1])
    int nnz = in_sizes[3] / 2;     // element count is 2*nnz for int32 or int64

    char* ws = (char*)d_ws;
    int*          flag  = (int*)ws;
    int*          cnt   = (int*)(ws + 64);
    unsigned int* claim = (unsigned int*)(ws + 1024);
    int*          slist = (int*)(ws + 1024 + B * L * 4);
    float*        sval  = (float*)(ws + 1024 + B * L * 4 + B * CAP * 4);

    k_init<<<B * L / 256, 256, 0, stream>>>(alpha, c, claim, cnt, (const int*)sidx, nnz, flag);
    k_scores<<<(nnz + 3) / 4, 256, 0, stream>>>(bdi, W2, sidx, nnz, flag, claim, cnt, slist, sval);
    k_ctx<<<B * S_CTX, 256, 0, stream>>>(att, cnt, slist, sval, alpha, c);
}

// Round 6
// 254.830 us; speedup vs baseline: 1.5898x; 1.5898x over previous
//
#include <hip/hip_runtime.h>
#include <math.h>

#define B 32
#define L 2048
#define V 512
#define D 512
#define S_CTX 32      // ctx blocks per batch; each owns a 64-wide l-shard
#define SH   (L / S_CTX)

// ws layout: 0: int flag; 1024: float scores[B*L] (256 KB)

// scores = -inf, c = 0; detect index dtype (one ballot).
// int64 encoding: odd int32 words in [nnz, 2*nnz) are high halves of idx0
// (< 32) == 0. int32 encoding: those words are idx1 values in [0, L).
__global__ __launch_bounds__(256) void k_init(float* __restrict__ scores,
        float* __restrict__ c, const int* __restrict__ idx32, int nnz,
        int* __restrict__ flag) {
    int i = blockIdx.x * 256 + threadIdx.x;   // grid covers exactly B*L
    scores[i] = -INFINITY;
    if (i < B * D) c[i] = 0.f;
    if (blockIdx.x == 0 && threadIdx.x < 64) {
        int step = nnz / 128; if (step < 1) step = 1;
        int w = nnz + 1 + 2 * threadIdx.x * step;
        unsigned long long nz = __ballot(idx32[w] != 0);
        if (threadIdx.x == 0) *flag = (nz == 0ull) ? 1 : 0;
    }
}

// scores[b,l] = dot(bdi[b,l,:], W2). One wave per nnz entry; duplicates write
// identical values (benign race). NO global counters/claims — R5 showed
// cross-XCD same-line atomics serialize at ~100M/s and cost 145 us.
// The reference also adds coef*(DHS@W1.T@W2)[b] — constant over the masked
// set; softmax is shift-invariant and scores are not an output, so the whole
// W1/DHS path drops out exactly.
__global__ __launch_bounds__(256) void k_scores(const float* __restrict__ bdi,
        const float* __restrict__ W2, const void* __restrict__ idx, int nnz,
        const int* __restrict__ flag, float* __restrict__ scores) {
    int wave = threadIdx.x >> 6, lane = threadIdx.x & 63;
    int e = blockIdx.x * 4 + wave;
    if (e >= nnz) return;
    int b, l;
    if (*flag) {
        const long long* q = (const long long*)idx;
        b = (int)q[e];
        l = (int)q[nnz + e];
    } else {
        const int* q = (const int*)idx;
        b = q[e];
        l = q[nnz + e];
    }
    const float4* row = (const float4*)(bdi + ((size_t)b * L + l) * V);
    const float4* w   = (const float4*)W2;
    float4 r0 = row[lane],      w0 = w[lane];
    float4 r1 = row[lane + 64], w1 = w[lane + 64];
    float acc = r0.x * w0.x + r0.y * w0.y + r0.z * w0.z + r0.w * w0.w
              + r1.x * w1.x + r1.y * w1.y + r1.z * w1.z + r1.w * w1.w;
    for (int off = 32; off; off >>= 1) acc += __shfl_down(acc, off, 64);
    if (lane == 0) scores[b * L + l] = acc;
}

// Fused softmax + dense alpha + context. Block (b,s): reduce the dense score
// row (L2/L3-hot, redundant across the 32 blocks of a batch), then handle
// ONLY the deterministic l-shard [s*64, s*64+64): write its dense alpha
// slice and gather its att rows into c. Block-local LDS compaction only.
__global__ __launch_bounds__(256) void k_ctx(const float* __restrict__ att,
        const float* __restrict__ scores, float* __restrict__ alpha,
        float* __restrict__ c) {
    int b = blockIdx.x >> 5, s = blockIdx.x & (S_CTX - 1);
    int tid = threadIdx.x;
    __shared__ float e_s[L];      // 8 KB
    __shared__ float red[256];
    __shared__ int   l_c[SH];
    __shared__ float a_c[SH];
    __shared__ int cnt;
    if (tid == 0) cnt = 0;
    const float4* srow = (const float4*)(scores + b * L);
    float4 v0 = srow[tid], v1 = srow[tid + 256];
    float m = fmaxf(fmaxf(fmaxf(v0.x, v0.y), fmaxf(v0.z, v0.w)),
                    fmaxf(fmaxf(v1.x, v1.y), fmaxf(v1.z, v1.w)));
    red[tid] = m;
    __syncthreads();
    for (int off = 128; off; off >>= 1) {
        if (tid < off) red[tid] = fmaxf(red[tid], red[tid + off]);
        __syncthreads();
    }
    m = red[0];
    __syncthreads();
    float4 e0, e1;
    e0.x = __expf(v0.x - m); e0.y = __expf(v0.y - m);
    e0.z = __expf(v0.z - m); e0.w = __expf(v0.w - m);
    e1.x = __expf(v1.x - m); e1.y = __expf(v1.y - m);
    e1.z = __expf(v1.z - m); e1.w = __expf(v1.w - m);
    ((float4*)e_s)[tid]       = e0;
    ((float4*)e_s)[tid + 256] = e1;
    red[tid] = e0.x + e0.y + e0.z + e0.w + e1.x + e1.y + e1.z + e1.w;
    __syncthreads();
    for (int off = 128; off; off >>= 1) {
        if (tid < off) red[tid] += red[tid + off];
        __syncthreads();
    }
    float inv = 1.f / red[0];
    // block-local compaction of this block's shard (order irrelevant)
    if (tid < SH) {
        int l = s * SH + tid;
        float e = e_s[l];
        if (e > 0.f) {
            int p = atomicAdd(&cnt, 1);   // LDS atomic — fast
            l_c[p] = l;
            a_c[p] = e * inv;
        }
    }
    // dense alpha slice for this shard: 64 floats = 16 float4
    if (tid < SH / 4) {
        float4 ev = ((const float4*)e_s)[s * (SH / 4) + tid];
        float4 av = {ev.x * inv, ev.y * inv, ev.z * inv, ev.w * inv};
        ((float4*)(alpha + b * L))[s * (SH / 4) + tid] = av;
    }
    __syncthreads();
    int n = cnt;
    int half = tid >> 7, dq = tid & 127;  // 2 rows per iteration, float4 lanes
    float4 acc = {0.f, 0.f, 0.f, 0.f};
    for (int j = half; j < n; j += 2) {
        float a = a_c[j];
        float4 v = *(const float4*)(att + ((size_t)b * L + l_c[j]) * D + dq * 4);
        acc.x += a * v.x;
        acc.y += a * v.y;
        acc.z += a * v.z;
        acc.w += a * v.w;
    }
    float* cb = c + b * D + dq * 4;
    atomicAdd(cb + 0, acc.x);
    atomicAdd(cb + 1, acc.y);
    atomicAdd(cb + 2, acc.z);
    atomicAdd(cb + 3, acc.w);
}

extern "C" void kernel_launch(void* const* d_in, const int* in_sizes, int n_in,
                              void* d_out, int out_size, void* d_ws, size_t ws_size,
                              hipStream_t stream) {
    const float* bdi  = (const float*)d_in[1];
    const float* att  = (const float*)d_in[2];
    const void*  sidx = d_in[3];
    const float* W2   = (const float*)d_in[6];

    float* out   = (float*)d_out;
    float* c     = out;            // [B, D]
    float* alpha = out + B * D;    // [B, L] (== [B,L,1])
    int nnz = in_sizes[3] / 2;     // element count is 2*nnz for int32 or int64

    char* ws = (char*)d_ws;
    int*   flag   = (int*)ws;
    float* scores = (float*)(ws + 1024);

    k_init<<<B * L / 256, 256, 0, stream>>>(scores, c, (const int*)sidx, nnz, flag);
    k_scores<<<(nnz + 3) / 4, 256, 0, stream>>>(bdi, W2, sidx, nnz, flag, scores);
    k_ctx<<<B * S_CTX, 256, 0, stream>>>(att, scores, alpha, c);
}